// Round 5
// baseline (241.826 us; speedup 1.0000x reference)
//
#include <hip/hip_runtime.h>
#include <math.h>

#define EPS 1e-5f
#define SCALE 0.17677669529663687f   // 1/sqrt(32)

// packed bf16 weight offsets in d_ws (ushort units)
#define OFF_We  0
#define OFF_Wf  16384
#define OFF_Wq  24576
#define OFF_Wk  40960
#define OFF_Wv  57344
#define OFF_Wo  73728
#define OFF_Wc1 90112
#define PACK_TOTAL 98304

#define CHUNK 4096    // ushorts per stage chunk (8 KB); 24 chunks total, linear in ws
#define NCHUNK 24
#define WAVES 8       // 512-thread block: 8 waves x 32 rows = 256 rows/block

typedef __bf16 bf16x8 __attribute__((ext_vector_type(8)));
typedef float f32x4 __attribute__((ext_vector_type(4)));
typedef unsigned short ushort_t;
typedef unsigned short ushortx4 __attribute__((ext_vector_type(4)));

// HW RNE conversion: compiler emits v_cvt_pk_bf16_f32 (pairs 2 converts / inst)
__device__ __forceinline__ ushort_t f2bf(float x) {
    return __builtin_bit_cast(ushort_t, (__bf16)x);
}
__device__ __forceinline__ float bf2f(ushort_t v) {
    unsigned u = ((unsigned)v) << 16;
    return __builtin_bit_cast(float, u);
}

// software RNE (kept for the pack kernel — not perf-critical, known-verified)
__device__ __forceinline__ ushort_t f2bf_sw(float x) {
    unsigned u = __builtin_bit_cast(unsigned, x);
    u = (u + 0x7fffu + ((u >> 16) & 1u)) >> 16;   // RNE
    return (ushort_t)u;
}

// 16-lane (DPP-row) all-lanes sum via row_ror butterfly — VALU pipe, no LDS.
#define DPPADD(x, ctrl) \
    ((x) + __builtin_bit_cast(float, __builtin_amdgcn_update_dpp( \
        __builtin_bit_cast(int, (x)), __builtin_bit_cast(int, (x)), (ctrl), 0xF, 0xF, false)))

__device__ __forceinline__ float rowsum16(float x) {
    x = DPPADD(x, 0x121);   // row_ror:1
    x = DPPADD(x, 0x122);   // row_ror:2
    x = DPPADD(x, 0x124);   // row_ror:4
    x = DPPADD(x, 0x128);   // row_ror:8
    return x;
}

// tanh-form GELU via sigmoid + HW exp; |err| <= ~4e-4 vs exact erf GELU
__device__ __forceinline__ float gelu_fast(float x) {
    float x2 = x * x;
    float u = x * fmaf(0.07135481283f, x2, 1.5957691216f);
    float e = __expf(-u);
    return x * __builtin_amdgcn_rcpf(1.0f + e);
}

// ---------------- weight pack kernel (verified r2/r3/r5/r7 — DO NOT TOUCH) ----------------
__global__ __launch_bounds__(256) void pack_all(
    const float* __restrict__ We, const float* __restrict__ Wf,
    const float* __restrict__ Wq, const float* __restrict__ Wk,
    const float* __restrict__ Wv, const float* __restrict__ Wo,
    const float* __restrict__ Wc1, ushort_t* __restrict__ ws)
{
    int o = blockIdx.x * 256 + threadIdx.x;
    if (o >= PACK_TOTAL) return;
    const float* W; int K, N, base;
    if (o < OFF_Wf)        { W = We;  K = 128; N = 128; base = OFF_We; }
    else if (o < OFF_Wq)   { W = Wf;  K = 64;  N = 128; base = OFF_Wf; }
    else if (o < OFF_Wk)   { W = Wq;  K = 128; N = 128; base = OFF_Wq; }
    else if (o < OFF_Wv)   { W = Wk;  K = 128; N = 128; base = OFF_Wk; }
    else if (o < OFF_Wo)   { W = Wv;  K = 128; N = 128; base = OFF_Wv; }
    else if (o < OFF_Wc1)  { W = Wo;  K = 128; N = 128; base = OFF_Wo; }
    else                   { W = Wc1; K = 128; N = 64;  base = OFF_Wc1; }
    int e = o - base;
    int j = e & 7, l = (e >> 3) & 63, rest = e >> 9;
    int KS = K >> 5;
    int s = rest % KS, t = rest / KS;
    int k = s * 32 + ((l >> 4) << 3) + j;
    int n = (t << 4) + (l & 15);
    ws[o] = f2bf_sw(W[k * N + n]);
}

// ---------------- GEMM helpers (A in regs, B from 8 KB LDS chunk) ----------------
template<int KS>
__device__ __forceinline__ void load_af(bf16x8 af[KS], const ushort_t* A, int lane)
{
    const int quad = lane >> 4, l16 = lane & 15;
    #pragma unroll
    for (int ks = 0; ks < KS; ++ks)
        af[ks] = *(const bf16x8*)(A + l16 * 136 + ks * 32 + quad * 8);
}

// 2-group chunk MFMA: each B fragment loaded ONCE, used by both row-groups.
template<int KS, int NT>
__device__ __forceinline__ void mma2(const bf16x8 a0[KS], const bf16x8 a1[KS],
                                     const ushort_t* sWb, f32x4* c0, f32x4* c1, int lane)
{
    #pragma unroll
    for (int t = 0; t < NT; ++t)
        #pragma unroll
        for (int ks = 0; ks < KS; ++ks) {
            bf16x8 bb = *(const bf16x8*)(sWb + ((t * KS + ks) * 64 + lane) * 8);
            c0[t] = __builtin_amdgcn_mfma_f32_16x16x32_bf16(a0[ks], bb, c0[t], 0, 0, 0);
            c1[t] = __builtin_amdgcn_mfma_f32_16x16x32_bf16(a1[ks], bb, c1[t], 0, 0, 0);
        }
}

// ---------------- main kernel: 8 waves x 32 wave-private rows (512 thr) ----------------
// Each wave owns TWO 16-row groups -> every LDS B-fragment feeds 2 (or 4) MFMAs.
// Weight staging: 24 x 8 KB chunks, double-buffered async DMA (global_load_lds),
// ONE barrier per chunk, issue one phase ahead.
__global__ __launch_bounds__(512, 1) void fusion_stage(
    const float* __restrict__ eeg, const float* __restrict__ fmri,
    const float* __restrict__ be, const float* __restrict__ ge, const float* __restrict__ bge,
    const float* __restrict__ bfb, const float* __restrict__ gf, const float* __restrict__ bgf,
    const float* __restrict__ bq, const float* __restrict__ bk, const float* __restrict__ bv,
    const float* __restrict__ bo,
    const float* __restrict__ fusion_logits, const float* __restrict__ temperature,
    const float* __restrict__ bc1, const float* __restrict__ gc, const float* __restrict__ bgc,
    const float* __restrict__ Wc2, const float* __restrict__ bc2,
    const ushort_t* __restrict__ ws, float* __restrict__ out)
{
    __shared__ __align__(16) ushort_t sW[2][CHUNK];         // 2 x 8 KB chunk buffers
    __shared__ __align__(16) ushort_t B1[WAVES][32 * 136];  // per-wave: eeg->ep->ctx->fused
    __shared__ __align__(16) ushort_t B2[WAVES][32 * 136];  // per-wave: fmri->fp

    const int tid = threadIdx.x;
    const int wave = tid >> 6, lane = tid & 63;
    const int quad = lane >> 4, l16 = lane & 15;
    const int rowbase = blockIdx.x * (WAVES * 32) + wave * 32;
    ushort_t* b1 = B1[wave];
    ushort_t* b2 = B2[wave];

    // async DMA one 8 KB chunk: 8 waves x (64 lanes x 16 B) = 8 KB
    auto prefetch = [&](int c) {
        const char* g = (const char*)(ws + c * CHUNK) + wave * 1024 + lane * 16;
        char* l = (char*)(sW[c & 1]) + wave * 1024;
        __builtin_amdgcn_global_load_lds(
            (const __attribute__((address_space(1))) void*)g,
            (__attribute__((address_space(3))) void*)l, 16, 0, 0);
    };

    int ck = 0;
    // barrier (drains c(ck) loads, issued a full phase ago); prefetch c(ck+1); return buf of c(ck)
    auto step = [&]() -> const ushort_t* {
        __syncthreads();
        if (ck + 1 < NCHUNK) prefetch(ck + 1);
        const ushort_t* p = sW[ck & 1];
        ++ck;
        return p;
    };

    prefetch(0);   // chunk 0 in flight while we stage inputs

    // ---- stage raw inputs -> bf16 A-layout LDS (wave-private, 32 rows) ----
    {
        const float4* src = (const float4*)(eeg + (size_t)rowbase * 128);
        #pragma unroll
        for (int i = 0; i < 16; ++i) {
            int idx = i * 64 + lane;               // 1024 float4 = 32 rows x 32
            float4 v = src[idx];
            int r = idx >> 5, k4 = (idx & 31) * 4;
            *(ushortx4*)&b1[r * 136 + k4] =
                (ushortx4){f2bf(v.x), f2bf(v.y), f2bf(v.z), f2bf(v.w)};
        }
        const float4* srcf = (const float4*)(fmri + (size_t)rowbase * 64);
        #pragma unroll
        for (int i = 0; i < 8; ++i) {
            int idx = i * 64 + lane;               // 512 float4 = 32 rows x 16
            float4 v = srcf[idx];
            int r = idx >> 4, k4 = (idx & 15) * 4;
            *(ushortx4*)&b2[r * 136 + k4] =
                (ushortx4){f2bf(v.x), f2bf(v.y), f2bf(v.z), f2bf(v.w)};
        }
    }

    // ---- S1: eeg @ We + be ; LN ; GELU -> ep (b1)  (chunks 0-3) ----
    {
        bf16x8 af0[4], af1[4];
        load_af<4>(af0, b1, lane);
        load_af<4>(af1, b1 + 16 * 136, lane);
        f32x4 acc[2][8];
        #pragma unroll
        for (int nt = 0; nt < 8; ++nt) {
            float b = be[nt * 16 + l16];
            acc[0][nt] = (f32x4){b, b, b, b};
            acc[1][nt] = (f32x4){b, b, b, b};
        }
        mma2<4, 2>(af0, af1, step(), acc[0] + 0, acc[1] + 0, lane);
        mma2<4, 2>(af0, af1, step(), acc[0] + 2, acc[1] + 2, lane);
        mma2<4, 2>(af0, af1, step(), acc[0] + 4, acc[1] + 4, lane);
        mma2<4, 2>(af0, af1, step(), acc[0] + 6, acc[1] + 6, lane);
        #pragma unroll
        for (int g = 0; g < 2; ++g) {
            float meanS[4], rstdS[4];
            #pragma unroll
            for (int r = 0; r < 4; ++r) {
                float s = 0.f, ss = 0.f;
                #pragma unroll
                for (int nt = 0; nt < 8; ++nt) { float x = acc[g][nt][r]; s += x; ss = fmaf(x, x, ss); }
                s = rowsum16(s); ss = rowsum16(ss);
                float m = s * (1.f / 128.f);
                meanS[r] = m;
                rstdS[r] = rsqrtf(ss * (1.f / 128.f) - m * m + EPS);
            }
            #pragma unroll
            for (int nt = 0; nt < 8; ++nt) {
                float gg = ge[nt * 16 + l16], bb = bge[nt * 16 + l16];
                #pragma unroll
                for (int r = 0; r < 4; ++r) {
                    float x = (acc[g][nt][r] - meanS[r]) * rstdS[r] * gg + bb;
                    b1[(g * 16 + quad * 4 + r) * 136 + nt * 16 + l16] = f2bf(gelu_fast(x));
                }
            }
        }
    }

    // ---- S2: fmri @ Wf + bf ; LN ; GELU -> fp (b2)  (chunks 4-5, KS=2) ----
    {
        bf16x8 af0[2], af1[2];
        load_af<2>(af0, b2, lane);
        load_af<2>(af1, b2 + 16 * 136, lane);
        f32x4 acc[2][8];
        #pragma unroll
        for (int nt = 0; nt < 8; ++nt) {
            float b = bfb[nt * 16 + l16];
            acc[0][nt] = (f32x4){b, b, b, b};
            acc[1][nt] = (f32x4){b, b, b, b};
        }
        mma2<2, 4>(af0, af1, step(), acc[0] + 0, acc[1] + 0, lane);
        mma2<2, 4>(af0, af1, step(), acc[0] + 4, acc[1] + 4, lane);
        #pragma unroll
        for (int g = 0; g < 2; ++g) {
            float meanS[4], rstdS[4];
            #pragma unroll
            for (int r = 0; r < 4; ++r) {
                float s = 0.f, ss = 0.f;
                #pragma unroll
                for (int nt = 0; nt < 8; ++nt) { float x = acc[g][nt][r]; s += x; ss = fmaf(x, x, ss); }
                s = rowsum16(s); ss = rowsum16(ss);
                float m = s * (1.f / 128.f);
                meanS[r] = m;
                rstdS[r] = rsqrtf(ss * (1.f / 128.f) - m * m + EPS);
            }
            #pragma unroll
            for (int nt = 0; nt < 8; ++nt) {
                float gg = gf[nt * 16 + l16], bb = bgf[nt * 16 + l16];
                #pragma unroll
                for (int r = 0; r < 4; ++r) {
                    float x = (acc[g][nt][r] - meanS[r]) * rstdS[r] * gg + bb;
                    b2[(g * 16 + quad * 4 + r) * 136 + nt * 16 + l16] = f2bf(gelu_fast(x));
                }
            }
        }
    }

    // persistent A-fragments for attention: ep (b1) and fp (b2), both groups
    bf16x8 afE[2][4], afF[2][4];
    load_af<4>(afE[0], b1, lane);
    load_af<4>(afE[1], b1 + 16 * 136, lane);
    load_af<4>(afF[0], b2, lane);
    load_af<4>(afF[1], b2 + 16 * 136, lane);

    // ---- S3: q = ep @ Wq + bq (held in regs)  (chunks 6-9) ----
    f32x4 q[2][8];
    {
        #pragma unroll
        for (int nt = 0; nt < 8; ++nt) {
            float b = bq[nt * 16 + l16];
            q[0][nt] = (f32x4){b, b, b, b};
            q[1][nt] = (f32x4){b, b, b, b};
        }
        mma2<4, 2>(afE[0], afE[1], step(), q[0] + 0, q[1] + 0, lane);
        mma2<4, 2>(afE[0], afE[1], step(), q[0] + 2, q[1] + 2, lane);
        mma2<4, 2>(afE[0], afE[1], step(), q[0] + 4, q[1] + 4, lane);
        mma2<4, 2>(afE[0], afE[1], step(), q[0] + 6, q[1] + 6, lane);
    }

    // ---- S4: single Wk pass; score DIFFERENCE (softmax == sigmoid)  (chunks 10-13) ----
    // Each B fragment feeds 4 MFMAs: e/f x 2 groups.
    float a0v[2][4][4];
    {
        float pd[2][4][4];
        #pragma unroll
        for (int g = 0; g < 2; ++g)
            #pragma unroll
            for (int h = 0; h < 4; ++h)
                #pragma unroll
                for (int r = 0; r < 4; ++r) pd[g][h][r] = 0.f;
        #pragma unroll
        for (int c = 0; c < 4; ++c) {
            const ushort_t* p = step();
            #pragma unroll
            for (int tl = 0; tl < 2; ++tl) {
                int nt = c * 2 + tl;
                f32x4 e0 = {0.f, 0.f, 0.f, 0.f}, f0 = {0.f, 0.f, 0.f, 0.f};
                f32x4 e1 = {0.f, 0.f, 0.f, 0.f}, f1 = {0.f, 0.f, 0.f, 0.f};
                #pragma unroll
                for (int ks = 0; ks < 4; ++ks) {
                    bf16x8 bb = *(const bf16x8*)(p + ((tl * 4 + ks) * 64 + lane) * 8);
                    e0 = __builtin_amdgcn_mfma_f32_16x16x32_bf16(afE[0][ks], bb, e0, 0, 0, 0);
                    f0 = __builtin_amdgcn_mfma_f32_16x16x32_bf16(afF[0][ks], bb, f0, 0, 0, 0);
                    e1 = __builtin_amdgcn_mfma_f32_16x16x32_bf16(afE[1][ks], bb, e1, 0, 0, 0);
                    f1 = __builtin_amdgcn_mfma_f32_16x16x32_bf16(afF[1][ks], bb, f1, 0, 0, 0);
                }
                int h = nt >> 1;
                #pragma unroll
                for (int r = 0; r < 4; ++r) {
                    pd[0][h][r] = fmaf(q[0][nt][r], e0[r] - f0[r], pd[0][h][r]);
                    pd[1][h][r] = fmaf(q[1][nt][r], e1[r] - f1[r], pd[1][h][r]);
                }
            }
        }
        #pragma unroll
        for (int g = 0; g < 2; ++g)
            #pragma unroll
            for (int h = 0; h < 4; ++h)
                #pragma unroll
                for (int r = 0; r < 4; ++r) {
                    float d = rowsum16(pd[g][h][r]) * SCALE;   // s0 - s1
                    a0v[g][h][r] = __builtin_amdgcn_rcpf(1.0f + __expf(-d));
                }
    }

    // ---- S5: ctx = a0*(ep@Wv) + (1-a0)*(fp@Wv) + bv -> b1 (bf16)  (chunks 14-17) ----
    #pragma unroll
    for (int c = 0; c < 4; ++c) {
        const ushort_t* p = step();
        #pragma unroll
        for (int tl = 0; tl < 2; ++tl) {
            int nt = c * 2 + tl;
            float b = bv[nt * 16 + l16];
            f32x4 e0 = {b, b, b, b}, f0 = {b, b, b, b};
            f32x4 e1 = {b, b, b, b}, f1 = {b, b, b, b};
            #pragma unroll
            for (int ks = 0; ks < 4; ++ks) {
                bf16x8 bb = *(const bf16x8*)(p + ((tl * 4 + ks) * 64 + lane) * 8);
                e0 = __builtin_amdgcn_mfma_f32_16x16x32_bf16(afE[0][ks], bb, e0, 0, 0, 0);
                f0 = __builtin_amdgcn_mfma_f32_16x16x32_bf16(afF[0][ks], bb, f0, 0, 0, 0);
                e1 = __builtin_amdgcn_mfma_f32_16x16x32_bf16(afE[1][ks], bb, e1, 0, 0, 0);
                f1 = __builtin_amdgcn_mfma_f32_16x16x32_bf16(afF[1][ks], bb, f1, 0, 0, 0);
            }
            int h = nt >> 1;
            #pragma unroll
            for (int r = 0; r < 4; ++r) {
                float a00 = a0v[0][h][r];
                float a01 = a0v[1][h][r];
                float c0 = a00 * e0[r] + (1.0f - a00) * f0[r];
                float c1 = a01 * e1[r] + (1.0f - a01) * f1[r];
                b1[(quad * 4 + r) * 136 + nt * 16 + l16] = f2bf(c0);
                b1[(16 + quad * 4 + r) * 136 + nt * 16 + l16] = f2bf(c1);
            }
        }
    }

    // ---- S6: eeg_enh = ctx @ Wo + bo ; learned fusion with fp  (chunks 18-21) ----
    {
        bf16x8 afC0[4], afC1[4];
        load_af<4>(afC0, b1, lane);
        load_af<4>(afC1, b1 + 16 * 136, lane);
        f32x4 acc[2][8];
        #pragma unroll
        for (int nt = 0; nt < 8; ++nt) {
            float b = bo[nt * 16 + l16];
            acc[0][nt] = (f32x4){b, b, b, b};
            acc[1][nt] = (f32x4){b, b, b, b};
        }
        mma2<4, 2>(afC0, afC1, step(), acc[0] + 0, acc[1] + 0, lane);
        mma2<4, 2>(afC0, afC1, step(), acc[0] + 2, acc[1] + 2, lane);
        mma2<4, 2>(afC0, afC1, step(), acc[0] + 4, acc[1] + 4, lane);
        mma2<4, 2>(afC0, afC1, step(), acc[0] + 6, acc[1] + 6, lane);
        float t = temperature[0];
        float dl = (fusion_logits[0] - fusion_logits[1]) / t;
        float w0 = __builtin_amdgcn_rcpf(1.0f + __expf(-dl));
        float w1 = 1.0f - w0;
        #pragma unroll
        for (int g = 0; g < 2; ++g)
            #pragma unroll
            for (int nt = 0; nt < 8; ++nt)
                #pragma unroll
                for (int r = 0; r < 4; ++r) {
                    int off = (g * 16 + quad * 4 + r) * 136 + nt * 16 + l16;
                    float fp = bf2f(b2[off]);
                    b1[off] = f2bf(w0 * acc[g][nt][r] + w1 * fp);
                }
    }

    // ---- S7: classifier: fused @ Wc1 + bc1 ; LN ; ReLU ; logits  (chunks 22-23) ----
    {
        bf16x8 afU0[4], afU1[4];
        load_af<4>(afU0, b1, lane);
        load_af<4>(afU1, b1 + 16 * 136, lane);
        f32x4 accH[2][4];
        #pragma unroll
        for (int nt = 0; nt < 4; ++nt) {
            float b = bc1[nt * 16 + l16];
            accH[0][nt] = (f32x4){b, b, b, b};
            accH[1][nt] = (f32x4){b, b, b, b};
        }
        mma2<4, 2>(afU0, afU1, step(), accH[0] + 0, accH[1] + 0, lane);
        mma2<4, 2>(afU0, afU1, step(), accH[0] + 2, accH[1] + 2, lane);
        float w2v[4][2];
        #pragma unroll
        for (int nt = 0; nt < 4; ++nt) {
            float2 w = *(const float2*)&Wc2[(nt * 16 + l16) * 2];
            w2v[nt][0] = w.x; w2v[nt][1] = w.y;
        }
        float o0c = bc2[0], o1c = bc2[1];
        #pragma unroll
        for (int g = 0; g < 2; ++g) {
            float meanS[4], rstdS[4];
            #pragma unroll
            for (int r = 0; r < 4; ++r) {
                float s = 0.f, ss = 0.f;
                #pragma unroll
                for (int nt = 0; nt < 4; ++nt) { float x = accH[g][nt][r]; s += x; ss = fmaf(x, x, ss); }
                s = rowsum16(s); ss = rowsum16(ss);
                float m = s * (1.f / 64.f);
                meanS[r] = m;
                rstdS[r] = rsqrtf(ss * (1.f / 64.f) - m * m + EPS);
            }
            float hv[4][4];
            #pragma unroll
            for (int nt = 0; nt < 4; ++nt) {
                float gg = gc[nt * 16 + l16], bb = bgc[nt * 16 + l16];
                #pragma unroll
                for (int r = 0; r < 4; ++r) {
                    float x = (accH[g][nt][r] - meanS[r]) * rstdS[r] * gg + bb;
                    hv[nt][r] = fmaxf(x, 0.0f);
                }
            }
            #pragma unroll
            for (int r = 0; r < 4; ++r) {
                float p0 = 0.f, p1 = 0.f;
                #pragma unroll
                for (int nt = 0; nt < 4; ++nt) {
                    p0 = fmaf(hv[nt][r], w2v[nt][0], p0);
                    p1 = fmaf(hv[nt][r], w2v[nt][1], p1);
                }
                p0 = rowsum16(p0); p1 = rowsum16(p1);
                if (l16 == 0) {
                    int row = rowbase + g * 16 + quad * 4 + r;
                    float2 o; o.x = p0 + o0c; o.y = p1 + o1c;
                    *(float2*)&out[row * 2] = o;
                }
            }
        }
    }
}

extern "C" void kernel_launch(void* const* d_in, const int* in_sizes, int n_in,
                              void* d_out, int out_size, void* d_ws, size_t ws_size,
                              hipStream_t stream) {
    const float* eeg  = (const float*)d_in[0];
    const float* fmri = (const float*)d_in[1];
    const float* We   = (const float*)d_in[2];
    const float* be   = (const float*)d_in[3];
    const float* ge   = (const float*)d_in[4];
    const float* bge  = (const float*)d_in[5];
    const float* Wf   = (const float*)d_in[6];
    const float* bf   = (const float*)d_in[7];
    const float* gf   = (const float*)d_in[8];
    const float* bgf  = (const float*)d_in[9];
    const float* Wq   = (const float*)d_in[10];
    const float* bq   = (const float*)d_in[11];
    const float* Wk   = (const float*)d_in[12];
    const float* bk   = (const float*)d_in[13];
    const float* Wv   = (const float*)d_in[14];
    const float* bv   = (const float*)d_in[15];
    const float* Wo   = (const float*)d_in[16];
    const float* bo   = (const float*)d_in[17];
    const float* fl   = (const float*)d_in[18];
    const float* temp = (const float*)d_in[19];
    const float* Wc1  = (const float*)d_in[20];
    const float* bc1  = (const float*)d_in[21];
    const float* gc   = (const float*)d_in[22];
    const float* bgc  = (const float*)d_in[23];
    const float* Wc2  = (const float*)d_in[24];
    const float* bc2  = (const float*)d_in[25];
    float* out = (float*)d_out;
    ushort_t* ws = (ushort_t*)d_ws;

    hipLaunchKernelGGL(pack_all, dim3((PACK_TOTAL + 255) / 256), dim3(256), 0, stream,
                       We, Wf, Wq, Wk, Wv, Wo, Wc1, ws);

    int B = in_sizes[0] / 128;     // 131072
    int grid = B / (WAVES * 32);   // 512 blocks x 512 threads (8 waves x 32 rows)
    hipLaunchKernelGGL(fusion_stage, dim3(grid), dim3(512), 0, stream,
                       eeg, fmri, be, ge, bge, bf, gf, bgf,
                       bq, bk, bv, bo, fl, temp, bc1, gc, bgc, Wc2, bc2,
                       ws, out);
}

// Round 7
// 204.805 us; speedup vs baseline: 1.1808x; 1.1808x over previous
//
#include <hip/hip_runtime.h>
#include <math.h>

#define EPS 1e-5f
#define SCALE 0.17677669529663687f   // 1/sqrt(32)

// packed bf16 weight offsets in d_ws (ushort units)
#define OFF_We  0
#define OFF_Wf  16384
#define OFF_Wq  24576
#define OFF_Wk  40960
#define OFF_Wv  57344
#define OFF_Wo  73728
#define OFF_Wc1 90112
#define PACK_TOTAL 98304

#define CHUNK 8192   // ushorts per stage chunk (16 KB = 4 n-tiles at KS=4)

typedef __bf16 bf16x8 __attribute__((ext_vector_type(8)));
typedef float f32x4 __attribute__((ext_vector_type(4)));
typedef unsigned short ushort_t;
typedef unsigned short ushortx4 __attribute__((ext_vector_type(4)));

// HW RNE conversion: compiler emits v_cvt_pk_bf16_f32 (verified bit-identical r4/r5)
__device__ __forceinline__ ushort_t f2bf(float x) {
    return __builtin_bit_cast(ushort_t, (__bf16)x);
}
__device__ __forceinline__ float bf2f(ushort_t v) {
    unsigned u = ((unsigned)v) << 16;
    return __builtin_bit_cast(float, u);
}

// software RNE (pack kernel only — verified, not perf-critical)
__device__ __forceinline__ ushort_t f2bf_sw(float x) {
    unsigned u = __builtin_bit_cast(unsigned, x);
    u = (u + 0x7fffu + ((u >> 16) & 1u)) >> 16;   // RNE
    return (ushort_t)u;
}

// 16-lane (DPP-row) all-lanes sum via row_ror butterfly — VALU pipe, no LDS.
#define DPPADD(x, ctrl) \
    ((x) + __builtin_bit_cast(float, __builtin_amdgcn_update_dpp( \
        __builtin_bit_cast(int, (x)), __builtin_bit_cast(int, (x)), (ctrl), 0xF, 0xF, false)))

__device__ __forceinline__ float rowsum16(float x) {
    x = DPPADD(x, 0x121);   // row_ror:1
    x = DPPADD(x, 0x122);   // row_ror:2
    x = DPPADD(x, 0x124);   // row_ror:4
    x = DPPADD(x, 0x128);   // row_ror:8
    return x;
}

// tanh-form GELU via sigmoid + HW exp2 (log2e folded into poly consts);
// |err| <= ~4e-4 vs exact erf GELU
__device__ __forceinline__ float gelu_fast(float x) {
    float x2 = x * x;
    // exponent = -x*(1.5957691216 + 0.07135481283*x2)*log2(e)
    float t = fmaf(-0.10294313843f, x2, -2.30220842f);
#if __has_builtin(__builtin_amdgcn_exp2f)
    float e = __builtin_amdgcn_exp2f(x * t);
#else
    float e = __expf(x * t * 0.6931471806f);
#endif
    return x * __builtin_amdgcn_rcpf(1.0f + e);
}

// ---------------- weight pack kernel (verified r2/r3/r5/r7 — DO NOT TOUCH) ----------------
__global__ __launch_bounds__(256) void pack_all(
    const float* __restrict__ We, const float* __restrict__ Wf,
    const float* __restrict__ Wq, const float* __restrict__ Wk,
    const float* __restrict__ Wv, const float* __restrict__ Wo,
    const float* __restrict__ Wc1, ushort_t* __restrict__ ws)
{
    int o = blockIdx.x * 256 + threadIdx.x;
    if (o >= PACK_TOTAL) return;
    const float* W; int K, N, base;
    if (o < OFF_Wf)        { W = We;  K = 128; N = 128; base = OFF_We; }
    else if (o < OFF_Wq)   { W = Wf;  K = 64;  N = 128; base = OFF_Wf; }
    else if (o < OFF_Wk)   { W = Wq;  K = 128; N = 128; base = OFF_Wk == OFF_Wk ? OFF_Wq : OFF_Wq; }
    else if (o < OFF_Wv)   { W = Wk;  K = 128; N = 128; base = OFF_Wk; }
    else if (o < OFF_Wo)   { W = Wv;  K = 128; N = 128; base = OFF_Wv; }
    else if (o < OFF_Wc1)  { W = Wo;  K = 128; N = 128; base = OFF_Wo; }
    else                   { W = Wc1; K = 128; N = 64;  base = OFF_Wc1; }
    int e = o - base;
    int j = e & 7, l = (e >> 3) & 63, rest = e >> 9;
    int KS = K >> 5;
    int s = rest % KS, t = rest / KS;
    int k = s * 32 + ((l >> 4) << 3) + j;
    int n = (t << 4) + (l & 15);
    ws[o] = f2bf_sw(W[k * N + n]);
}

// ---------------- GEMM helpers (A in regs, B from 16 KB LDS chunk) ----------------
template<int KS>
__device__ __forceinline__ void load_af(bf16x8 af[KS], const ushort_t* A, int lane)
{
    const int quad = lane >> 4, l16 = lane & 15;
    #pragma unroll
    for (int ks = 0; ks < KS; ++ks)
        af[ks] = *(const bf16x8*)(A + l16 * 136 + ks * 32 + quad * 8);
}

// chunk-local MFMA: sW holds NT4 n-tiles, accumulate into acc[0..NT4)
template<int KS, int NT4>
__device__ __forceinline__ void mma_c(const bf16x8 af[KS], const ushort_t* sW,
                                      f32x4* acc, int lane)
{
    #pragma unroll
    for (int t = 0; t < NT4; ++t)
        #pragma unroll
        for (int ks = 0; ks < KS; ++ks) {
            bf16x8 bb = *(const bf16x8*)(sW + ((t * KS + ks) * 64 + lane) * 8);
            acc[t] = __builtin_amdgcn_mfma_f32_16x16x32_bf16(af[ks], bb, acc[t], 0, 0, 0);
        }
}

// ---------------- main kernel: 4 waves x 16 wave-private rows, 16 KB chunked staging ----------------
__global__ __launch_bounds__(256, 3) void fusion_stage(
    const float* __restrict__ eeg, const float* __restrict__ fmri,
    const float* __restrict__ be, const float* __restrict__ ge, const float* __restrict__ bge,
    const float* __restrict__ bfb, const float* __restrict__ gf, const float* __restrict__ bgf,
    const float* __restrict__ bq, const float* __restrict__ bk, const float* __restrict__ bv,
    const float* __restrict__ bo,
    const float* __restrict__ fusion_logits, const float* __restrict__ temperature,
    const float* __restrict__ bc1, const float* __restrict__ gc, const float* __restrict__ bgc,
    const float* __restrict__ Wc2, const float* __restrict__ bc2,
    const ushort_t* __restrict__ ws, float* __restrict__ out)
{
    __shared__ __align__(16) ushort_t sW[CHUNK];        // 16 KB weight chunk buffer
    __shared__ __align__(16) ushort_t B1[4][16 * 136];  // per-wave: eeg->ep->ctx->fused
    __shared__ __align__(16) ushort_t B2[4][16 * 136];  // per-wave: fmri->fp

    const int tid = threadIdx.x;
    const int wave = tid >> 6, lane = tid & 63;
    const int quad = lane >> 4, l16 = lane & 15;
    const int rowbase = blockIdx.x * 64 + wave * 16;
    ushort_t* b1 = B1[wave];
    ushort_t* b2 = B2[wave];

    // cooperative chunk copy via async DMA: barrier(prev consumed) ; issue 16 KB of
    // global_load_lds ; barrier (drains vmcnt -> data visible)
    auto stageW = [&](int offU) {
        __syncthreads();
        const char* g = (const char*)(ws + offU) + tid * 16;
        char* l = (char*)sW + tid * 16;
        #pragma unroll
        for (int i = 0; i < 4; ++i)
            __builtin_amdgcn_global_load_lds(
                (const __attribute__((address_space(1))) void*)(g + i * 4096),
                (__attribute__((address_space(3))) void*)(l + i * 4096), 16, 0, 0);
        __syncthreads();
    };

    // ---- stage raw inputs -> bf16 A-layout LDS (wave-private) ----
    {
        const float4* src = (const float4*)(eeg + (size_t)rowbase * 128);
        #pragma unroll
        for (int i = 0; i < 8; ++i) {
            int idx = i * 64 + lane;               // 512 float4 = 16 rows x 32
            float4 v = src[idx];
            int r = idx >> 5, k4 = (idx & 31) * 4;
            *(ushortx4*)&b1[r * 136 + k4] =
                (ushortx4){f2bf(v.x), f2bf(v.y), f2bf(v.z), f2bf(v.w)};
        }
        const float4* srcf = (const float4*)(fmri + (size_t)rowbase * 64);
        #pragma unroll
        for (int i = 0; i < 4; ++i) {
            int idx = i * 64 + lane;               // 256 float4 = 16 rows x 16
            float4 v = srcf[idx];
            int r = idx >> 4, k4 = (idx & 15) * 4;
            *(ushortx4*)&b2[r * 136 + k4] =
                (ushortx4){f2bf(v.x), f2bf(v.y), f2bf(v.z), f2bf(v.w)};
        }
    }

    float meanS[4], rstdS[4];

    // ---- S1: eeg @ We + be ; LN ; GELU -> ep (b1) ----
    {
        bf16x8 afR[4]; load_af<4>(afR, b1, lane);
        f32x4 acc[8];
        #pragma unroll
        for (int nt = 0; nt < 8; ++nt) {
            float b = be[nt * 16 + l16];
            acc[nt] = (f32x4){b, b, b, b};
        }
        stageW(OFF_We);          mma_c<4, 4>(afR, sW, acc + 0, lane);
        stageW(OFF_We + CHUNK);  mma_c<4, 4>(afR, sW, acc + 4, lane);
        #pragma unroll
        for (int r = 0; r < 4; ++r) {
            float s = 0.f, ss = 0.f;
            #pragma unroll
            for (int nt = 0; nt < 8; ++nt) { float x = acc[nt][r]; s += x; ss = fmaf(x, x, ss); }
            s = rowsum16(s); ss = rowsum16(ss);
            float m = s * (1.f / 128.f);
            meanS[r] = m;
            rstdS[r] = rsqrtf(ss * (1.f / 128.f) - m * m + EPS);
        }
        #pragma unroll
        for (int nt = 0; nt < 8; ++nt) {
            float g = ge[nt * 16 + l16], bb = bge[nt * 16 + l16];
            #pragma unroll
            for (int r = 0; r < 4; ++r) {
                float x = (acc[nt][r] - meanS[r]) * rstdS[r] * g + bb;
                b1[(quad * 4 + r) * 136 + nt * 16 + l16] = f2bf(gelu_fast(x));
            }
        }
    }

    // ---- S2: fmri @ Wf + bf ; LN ; GELU -> fp (b2 + f32 regs)  (KS=2: one chunk) ----
    f32x4 fpv[8];   // f32 GELU outputs, kept alive for the S6 fusion blend
    {
        bf16x8 afR[2]; load_af<2>(afR, b2, lane);
        f32x4 acc[8];
        #pragma unroll
        for (int nt = 0; nt < 8; ++nt) {
            float b = bfb[nt * 16 + l16];
            acc[nt] = (f32x4){b, b, b, b};
        }
        stageW(OFF_Wf);  mma_c<2, 8>(afR, sW, acc, lane);
        #pragma unroll
        for (int r = 0; r < 4; ++r) {
            float s = 0.f, ss = 0.f;
            #pragma unroll
            for (int nt = 0; nt < 8; ++nt) { float x = acc[nt][r]; s += x; ss = fmaf(x, x, ss); }
            s = rowsum16(s); ss = rowsum16(ss);
            float m = s * (1.f / 128.f);
            meanS[r] = m;
            rstdS[r] = rsqrtf(ss * (1.f / 128.f) - m * m + EPS);
        }
        #pragma unroll
        for (int nt = 0; nt < 8; ++nt) {
            float g = gf[nt * 16 + l16], bb = bgf[nt * 16 + l16];
            #pragma unroll
            for (int r = 0; r < 4; ++r) {
                float x = (acc[nt][r] - meanS[r]) * rstdS[r] * g + bb;
                float gv = gelu_fast(x);
                fpv[nt][r] = gv;
                b2[(quad * 4 + r) * 136 + nt * 16 + l16] = f2bf(gv);
            }
        }
    }

    // persistent A-fragments for attention: ep (b1) and fp (b2)
    bf16x8 afE[4]; load_af<4>(afE, b1, lane);
    bf16x8 afF[4]; load_af<4>(afF, b2, lane);

    // ---- S3: q = ep @ Wq + bq (held in regs) ----
    f32x4 q[8];
    {
        #pragma unroll
        for (int nt = 0; nt < 8; ++nt) {
            float b = bq[nt * 16 + l16];
            q[nt] = (f32x4){b, b, b, b};
        }
        stageW(OFF_Wq);          mma_c<4, 4>(afE, sW, q + 0, lane);
        stageW(OFF_Wq + CHUNK);  mma_c<4, 4>(afE, sW, q + 4, lane);
    }

    // ---- S4: single Wk pass; accumulate score DIFFERENCE (softmax == sigmoid) ----
    float a0v[4][4];
    {
        float pd[4][4];
        #pragma unroll
        for (int h = 0; h < 4; ++h)
            #pragma unroll
            for (int r = 0; r < 4; ++r) pd[h][r] = 0.f;
        #pragma unroll
        for (int c = 0; c < 2; ++c) {
            stageW(OFF_Wk + c * CHUNK);
            #pragma unroll
            for (int tl = 0; tl < 4; ++tl) {
                int nt = c * 4 + tl;
                f32x4 e = {0.f, 0.f, 0.f, 0.f}, f = {0.f, 0.f, 0.f, 0.f};
                #pragma unroll
                for (int ks = 0; ks < 4; ++ks) {
                    bf16x8 bb = *(const bf16x8*)(sW + ((tl * 4 + ks) * 64 + lane) * 8);
                    e = __builtin_amdgcn_mfma_f32_16x16x32_bf16(afE[ks], bb, e, 0, 0, 0);
                    f = __builtin_amdgcn_mfma_f32_16x16x32_bf16(afF[ks], bb, f, 0, 0, 0);
                }
                int h = nt >> 1;
                #pragma unroll
                for (int r = 0; r < 4; ++r)
                    pd[h][r] = fmaf(q[nt][r], e[r] - f[r], pd[h][r]);
            }
        }
        #pragma unroll
        for (int h = 0; h < 4; ++h)
            #pragma unroll
            for (int r = 0; r < 4; ++r) {
                float d = rowsum16(pd[h][r]) * SCALE;   // s0 - s1
                a0v[h][r] = __builtin_amdgcn_rcpf(1.0f + __expf(-d));
            }
    }

    // ---- S5: ctx = f + a0*(e - f) (biases folded) -> b1 (bf16) ----
    #pragma unroll
    for (int c = 0; c < 2; ++c) {
        stageW(OFF_Wv + c * CHUNK);
        #pragma unroll
        for (int tl = 0; tl < 4; ++tl) {
            int nt = c * 4 + tl;
            float b = bv[nt * 16 + l16];
            f32x4 e = {b, b, b, b}, f = {b, b, b, b};
            #pragma unroll
            for (int ks = 0; ks < 4; ++ks) {
                bf16x8 bb = *(const bf16x8*)(sW + ((tl * 4 + ks) * 64 + lane) * 8);
                e = __builtin_amdgcn_mfma_f32_16x16x32_bf16(afE[ks], bb, e, 0, 0, 0);
                f = __builtin_amdgcn_mfma_f32_16x16x32_bf16(afF[ks], bb, f, 0, 0, 0);
            }
            int h = nt >> 1;
            #pragma unroll
            for (int r = 0; r < 4; ++r) {
                float c0 = fmaf(a0v[h][r], e[r] - f[r], f[r]);
                b1[(quad * 4 + r) * 136 + nt * 16 + l16] = f2bf(c0);
            }
        }
    }

    // ---- S6: eeg_enh = ctx @ Wo + bo ; learned fusion with fp (f32 regs) ----
    {
        bf16x8 afC[4]; load_af<4>(afC, b1, lane);
        f32x4 acc[8];
        #pragma unroll
        for (int nt = 0; nt < 8; ++nt) {
            float b = bo[nt * 16 + l16];
            acc[nt] = (f32x4){b, b, b, b};
        }
        stageW(OFF_Wo);          mma_c<4, 4>(afC, sW, acc + 0, lane);
        stageW(OFF_Wo + CHUNK);  mma_c<4, 4>(afC, sW, acc + 4, lane);
        float t = temperature[0];
        float dl = (fusion_logits[0] - fusion_logits[1]) / t;
        float w0 = __builtin_amdgcn_rcpf(1.0f + __expf(-dl));
        float w1 = 1.0f - w0;
        #pragma unroll
        for (int nt = 0; nt < 8; ++nt)
            #pragma unroll
            for (int r = 0; r < 4; ++r) {
                int off = (quad * 4 + r) * 136 + nt * 16 + l16;
                b1[off] = f2bf(w0 * acc[nt][r] + w1 * fpv[nt][r]);
            }
    }

    // ---- S7: classifier: fused @ Wc1 + bc1 ; LN ; ReLU ; logits ----
    {
        bf16x8 afU[4]; load_af<4>(afU, b1, lane);
        f32x4 accH[4];
        #pragma unroll
        for (int nt = 0; nt < 4; ++nt) {
            float b = bc1[nt * 16 + l16];
            accH[nt] = (f32x4){b, b, b, b};
        }
        stageW(OFF_Wc1);  mma_c<4, 4>(afU, sW, accH, lane);
        #pragma unroll
        for (int r = 0; r < 4; ++r) {
            float s = 0.f, ss = 0.f;
            #pragma unroll
            for (int nt = 0; nt < 4; ++nt) { float x = accH[nt][r]; s += x; ss = fmaf(x, x, ss); }
            s = rowsum16(s); ss = rowsum16(ss);
            float m = s * (1.f / 64.f);
            meanS[r] = m;
            rstdS[r] = rsqrtf(ss * (1.f / 64.f) - m * m + EPS);
        }
        float hv[4][4];
        #pragma unroll
        for (int nt = 0; nt < 4; ++nt) {
            float g = gc[nt * 16 + l16], bb = bgc[nt * 16 + l16];
            #pragma unroll
            for (int r = 0; r < 4; ++r) {
                float x = (accH[nt][r] - meanS[r]) * rstdS[r] * g + bb;
                hv[nt][r] = fmaxf(x, 0.0f);
            }
        }
        float w2v[4][2];
        #pragma unroll
        for (int nt = 0; nt < 4; ++nt) {
            float2 w = *(const float2*)&Wc2[(nt * 16 + l16) * 2];
            w2v[nt][0] = w.x; w2v[nt][1] = w.y;
        }
        float o0c = bc2[0], o1c = bc2[1];
        #pragma unroll
        for (int r = 0; r < 4; ++r) {
            float p0 = 0.f, p1 = 0.f;
            #pragma unroll
            for (int nt = 0; nt < 4; ++nt) {
                p0 = fmaf(hv[nt][r], w2v[nt][0], p0);
                p1 = fmaf(hv[nt][r], w2v[nt][1], p1);
            }
            p0 = rowsum16(p0); p1 = rowsum16(p1);
            if (l16 == 0) {
                int row = rowbase + quad * 4 + r;
                float2 o; o.x = p0 + o0c; o.y = p1 + o1c;
                *(float2*)&out[row * 2] = o;
            }
        }
    }
}

extern "C" void kernel_launch(void* const* d_in, const int* in_sizes, int n_in,
                              void* d_out, int out_size, void* d_ws, size_t ws_size,
                              hipStream_t stream) {
    const float* eeg  = (const float*)d_in[0];
    const float* fmri = (const float*)d_in[1];
    const float* We   = (const float*)d_in[2];
    const float* be   = (const float*)d_in[3];
    const float* ge   = (const float*)d_in[4];
    const float* bge  = (const float*)d_in[5];
    const float* Wf   = (const float*)d_in[6];
    const float* bf   = (const float*)d_in[7];
    const float* gf   = (const float*)d_in[8];
    const float* bgf  = (const float*)d_in[9];
    const float* Wq   = (const float*)d_in[10];
    const float* bq   = (const float*)d_in[11];
    const float* Wk   = (const float*)d_in[12];
    const float* bk   = (const float*)d_in[13];
    const float* Wv   = (const float*)d_in[14];
    const float* bv   = (const float*)d_in[15];
    const float* Wo   = (const float*)d_in[16];
    const float* bo   = (const float*)d_in[17];
    const float* fl   = (const float*)d_in[18];
    const float* temp = (const float*)d_in[19];
    const float* Wc1  = (const float*)d_in[20];
    const float* bc1  = (const float*)d_in[21];
    const float* gc   = (const float*)d_in[22];
    const float* bgc  = (const float*)d_in[23];
    const float* Wc2  = (const float*)d_in[24];
    const float* bc2  = (const float*)d_in[25];
    float* out = (float*)d_out;
    ushort_t* ws = (ushort_t*)d_ws;

    hipLaunchKernelGGL(pack_all, dim3((PACK_TOTAL + 255) / 256), dim3(256), 0, stream,
                       We, Wf, Wq, Wk, Wv, Wo, Wc1, ws);

    int B = in_sizes[0] / 128;     // 131072
    int grid = B / 64;             // 2048 blocks x 256 threads (4 waves x 16 rows)
    hipLaunchKernelGGL(fusion_stage, dim3(grid), dim3(256), 0, stream,
                       eeg, fmri, be, ge, bge, bf, gf, bgf,
                       bq, bk, bv, bo, fl, temp, bc1, gc, bgc, Wc2, bc2,
                       ws, out);
}